// Round 12
// baseline (152.471 us; speedup 1.0000x reference)
//
#include <hip/hip_runtime.h>

constexpr int NBINS = 256;
constexpr int HPI = 3 * NBINS;  // 768 bins per image (3 channels)
constexpr int BPI = 24;         // blocks per image: 64*24=1536 = exactly 6 blocks/CU

typedef int iv4 __attribute__((ext_vector_type(4)));

// ---------------- Kernel 1: partial histograms + packed uint8 copy ----------------
// R8 structure exactly (best measured): normal input loads (LLC-resident
// across graph replays), normal packed stores (LLC-served for kernel 3),
// plain per-block partial stores. Element of v.x is 4*i; (4*i)%3 == i%3;
// stride%3==0 keeps channel phase loop-invariant.
__global__ __launch_bounds__(256)
void hist_part_kernel(const iv4* __restrict__ in, int* __restrict__ part,
                      unsigned* __restrict__ packed, int n4_per_img) {
    __shared__ int subh[4][HPI];  // per-wave sub-histograms, 12 KB
    const int tid = threadIdx.x;
    const int wave = tid >> 6;

    for (int i = tid; i < 4 * HPI; i += 256) ((int*)subh)[i] = 0;
    __syncthreads();

    const int img = blockIdx.x / BPI;
    const int blk = blockIdx.x % BPI;
    const size_t ibase = (size_t)img * n4_per_img;
    const iv4* p = in + ibase;
    unsigned* pk = packed + ibase;
    const int stride = BPI * 256;  // 6144, divisible by 3

    int i = blk * 256 + tid;
    int c0 = i % 3;
    int c1 = c0 + 1; if (c1 == 3) c1 = 0;
    int c2 = c1 + 1; if (c2 == 3) c2 = 0;
    int c3 = c2 + 1; if (c3 == 3) c3 = 0;
    const int b0 = c0 * NBINS, b1 = c1 * NBINS, b2 = c2 * NBINS, b3 = c3 * NBINS;

    for (; i + stride < n4_per_img; i += 2 * stride) {
        iv4 v0 = p[i];
        iv4 v1 = p[i + stride];
        pk[i]          = (unsigned)(v0.x & 255) | ((unsigned)(v0.y & 255) << 8) |
                         ((unsigned)(v0.z & 255) << 16) | ((unsigned)(v0.w & 255) << 24);
        pk[i + stride] = (unsigned)(v1.x & 255) | ((unsigned)(v1.y & 255) << 8) |
                         ((unsigned)(v1.z & 255) << 16) | ((unsigned)(v1.w & 255) << 24);
        atomicAdd(&subh[wave][b0 + (v0.x & 255)], 1);
        atomicAdd(&subh[wave][b1 + (v0.y & 255)], 1);
        atomicAdd(&subh[wave][b2 + (v0.z & 255)], 1);
        atomicAdd(&subh[wave][b3 + (v0.w & 255)], 1);
        atomicAdd(&subh[wave][b0 + (v1.x & 255)], 1);
        atomicAdd(&subh[wave][b1 + (v1.y & 255)], 1);
        atomicAdd(&subh[wave][b2 + (v1.z & 255)], 1);
        atomicAdd(&subh[wave][b3 + (v1.w & 255)], 1);
    }
    if (i < n4_per_img) {
        iv4 v = p[i];
        pk[i] = (unsigned)(v.x & 255) | ((unsigned)(v.y & 255) << 8) |
                ((unsigned)(v.z & 255) << 16) | ((unsigned)(v.w & 255) << 24);
        atomicAdd(&subh[wave][b0 + (v.x & 255)], 1);
        atomicAdd(&subh[wave][b1 + (v.y & 255)], 1);
        atomicAdd(&subh[wave][b2 + (v.z & 255)], 1);
        atomicAdd(&subh[wave][b3 + (v.w & 255)], 1);
    }
    __syncthreads();

    int* gp = part + (size_t)blockIdx.x * HPI;  // own slot: plain store, no atomics
    for (int e = tid; e < HPI; e += 256)
        gp[e] = subh[0][e] + subh[1][e] + subh[2][e] + subh[3][e];
}

// ---------------- Kernel 2: reduce partials + LUT (wave-shfl scan, 3 barriers) ----
__global__ __launch_bounds__(256)
void lut_kernel(const int* __restrict__ part, int* __restrict__ lut) {
    __shared__ int waveTot[4];
    __shared__ int waveHi[4];
    __shared__ int hlS;

    const int t    = threadIdx.x;
    const int wave = t >> 6;
    const int lane = t & 63;
    const int img  = blockIdx.x / 3;
    const int ch   = blockIdx.x % 3;

    const int* p = part + (size_t)img * BPI * HPI + ch * NBINS + t;
    int h = 0;
    #pragma unroll 4
    for (int b = 0; b < BPI; ++b) h += p[(size_t)b * HPI];

    // inclusive scan within wave (no barriers)
    int cum = h;
    #pragma unroll
    for (int d = 1; d < 64; d <<= 1) {
        int v = __shfl_up(cum, d, 64);
        if (lane >= d) cum += v;
    }

    unsigned long long nzmask = __ballot(h > 0);
    if (lane == 63) waveTot[wave] = cum;
    if (lane == 0)
        waveHi[wave] = nzmask ? (wave * 64 + 63 - __clzll(nzmask)) : -1;
    __syncthreads();  // barrier 1

    int add = 0, sum = 0;
    #pragma unroll
    for (int w = 0; w < 4; ++w) {
        int tt = waveTot[w];
        if (w < wave) add += tt;
        sum += tt;
    }
    cum += add;

    int last = max(max(waveHi[0], waveHi[1]), max(waveHi[2], waveHi[3]));
    if (t == last) hlS = h;  // broadcast histo[last]
    __syncthreads();  // barrier 2

    const int step = (sum - hlS) / 255;
    int v;
    if (step == 0) {
        v = t;  // reference: where(step==0, img, ...)
    } else {
        const int cp = cum - h;  // exclusive prefix (== concat([0], cumsum[:-1]))
        v = (cp + (step >> 1)) / step;
        if (v > 255) v = 255;
    }
    lut[blockIdx.x * NBINS + t] = v;
}

// ---------------- Kernel 3: apply LUT, uint2 packed in (8B/lane) / nt-iv4 out ----
// Per thread: 8 consecutive pixels per uint2; stride in elements = 8*6144
// divisible by 3 -> starting channel phase p = (8u)%3 is loop-invariant.
// 98304/6144 = 16 uint2 iters/thread, unroll x2 -> 8 exact iterations, no tail.
__global__ __launch_bounds__(256)
void apply_kernel(const uint2* __restrict__ packed2, iv4* __restrict__ out,
                  const int* __restrict__ lut, int n2_per_img) {
    __shared__ int l[HPI];
    const int tid = threadIdx.x;
    const int img = blockIdx.x / BPI;
    const int blk = blockIdx.x % BPI;

    const int* gl = lut + (size_t)img * HPI;
    for (int i = tid; i < HPI; i += 256) l[i] = gl[i];
    __syncthreads();

    const uint2* pk = packed2 + (size_t)img * n2_per_img;
    iv4* q = out + (size_t)img * n2_per_img * 2;  // 1 uint2 -> 2 iv4
    const int stride2 = BPI * 256;  // uint2 units; element stride 8*6144 % 3 == 0

    int u = blk * 256 + tid;
    // channel bases for the 8 consecutive elements this thread owns per uint2
    int ph = (int)(((long long)u * 8) % 3);
    int b[8];
    #pragma unroll
    for (int k = 0; k < 8; ++k) {
        b[k] = ph * NBINS;
        ph = (ph == 2) ? 0 : ph + 1;
    }

    for (; u + stride2 < n2_per_img; u += 2 * stride2) {
        uint2 w0 = pk[u];
        uint2 w1 = pk[u + stride2];
        iv4 o0, o1, o2, o3;
        o0.x = l[b[0] + (w0.x & 255)];
        o0.y = l[b[1] + ((w0.x >> 8) & 255)];
        o0.z = l[b[2] + ((w0.x >> 16) & 255)];
        o0.w = l[b[3] + (w0.x >> 24)];
        o1.x = l[b[4] + (w0.y & 255)];
        o1.y = l[b[5] + ((w0.y >> 8) & 255)];
        o1.z = l[b[6] + ((w0.y >> 16) & 255)];
        o1.w = l[b[7] + (w0.y >> 24)];
        o2.x = l[b[0] + (w1.x & 255)];
        o2.y = l[b[1] + ((w1.x >> 8) & 255)];
        o2.z = l[b[2] + ((w1.x >> 16) & 255)];
        o2.w = l[b[3] + (w1.x >> 24)];
        o3.x = l[b[4] + (w1.y & 255)];
        o3.y = l[b[5] + ((w1.y >> 8) & 255)];
        o3.z = l[b[6] + ((w1.y >> 16) & 255)];
        o3.w = l[b[7] + (w1.y >> 24)];
        __builtin_nontemporal_store(o0, &q[2 * u]);
        __builtin_nontemporal_store(o1, &q[2 * u + 1]);
        __builtin_nontemporal_store(o2, &q[2 * (u + stride2)]);
        __builtin_nontemporal_store(o3, &q[2 * (u + stride2) + 1]);
    }
    if (u < n2_per_img) {
        uint2 w = pk[u];
        iv4 o0, o1;
        o0.x = l[b[0] + (w.x & 255)];
        o0.y = l[b[1] + ((w.x >> 8) & 255)];
        o0.z = l[b[2] + ((w.x >> 16) & 255)];
        o0.w = l[b[3] + (w.x >> 24)];
        o1.x = l[b[4] + (w.y & 255)];
        o1.y = l[b[5] + ((w.y >> 8) & 255)];
        o1.z = l[b[6] + ((w.y >> 16) & 255)];
        o1.w = l[b[7] + (w.y >> 24)];
        __builtin_nontemporal_store(o0, &q[2 * u]);
        __builtin_nontemporal_store(o1, &q[2 * u + 1]);
    }
}

extern "C" void kernel_launch(void* const* d_in, const int* in_sizes, int n_in,
                              void* d_out, int out_size, void* d_ws, size_t ws_size,
                              hipStream_t stream) {
    const int* in = (const int*)d_in[0];
    int* out = (int*)d_out;

    const int npix = 512 * 512;
    const int ints_per_img = 3 * npix;
    const int n4_per_img = ints_per_img / 4;        // 196608 (= 32 * 6144)
    const int n2_per_img = ints_per_img / 8;        // 98304  (= 16 * 6144)
    const int n_img = in_sizes[0] / ints_per_img;   // 64

    int* part = (int*)d_ws;                             // 1536*768 ints = 4.7 MB
    int* lut  = part + (size_t)n_img * BPI * HPI;       // 192 KB
    unsigned* packed = (unsigned*)(lut + (size_t)n_img * HPI);  // 50 MB

    hist_part_kernel<<<n_img * BPI, 256, 0, stream>>>((const iv4*)in, part, packed, n4_per_img);
    lut_kernel<<<n_img * 3, 256, 0, stream>>>(part, lut);
    apply_kernel<<<n_img * BPI, 256, 0, stream>>>((const uint2*)packed, (iv4*)out, lut, n2_per_img);
}

// Round 13
// 85.032 us; speedup vs baseline: 1.7931x; 1.7931x over previous
//
#include <hip/hip_runtime.h>

constexpr int NBINS = 256;
constexpr int HPI = 3 * NBINS;  // 768 bins per image (3 channels)
constexpr int BPI = 24;         // blocks per image: 64*24=1536 = exactly 6 blocks/CU

typedef int iv4 __attribute__((ext_vector_type(4)));

// ---------------- Kernel 1: partial histograms + packed uint8 copy ----------------
// R8 structure exactly (best measured): normal input loads (LLC-resident
// across graph replays), normal packed stores (LLC-served for kernel 3),
// plain per-block partial stores. Element of v.x is 4*i; (4*i)%3 == i%3;
// stride%3==0 keeps channel phase loop-invariant.
__global__ __launch_bounds__(256)
void hist_part_kernel(const iv4* __restrict__ in, int* __restrict__ part,
                      unsigned* __restrict__ packed, int n4_per_img) {
    __shared__ int subh[4][HPI];  // per-wave sub-histograms, 12 KB
    const int tid = threadIdx.x;
    const int wave = tid >> 6;

    for (int i = tid; i < 4 * HPI; i += 256) ((int*)subh)[i] = 0;
    __syncthreads();

    const int img = blockIdx.x / BPI;
    const int blk = blockIdx.x % BPI;
    const size_t ibase = (size_t)img * n4_per_img;
    const iv4* p = in + ibase;
    unsigned* pk = packed + ibase;
    const int stride = BPI * 256;  // 6144, divisible by 3

    int i = blk * 256 + tid;
    int c0 = i % 3;
    int c1 = c0 + 1; if (c1 == 3) c1 = 0;
    int c2 = c1 + 1; if (c2 == 3) c2 = 0;
    int c3 = c2 + 1; if (c3 == 3) c3 = 0;
    const int b0 = c0 * NBINS, b1 = c1 * NBINS, b2 = c2 * NBINS, b3 = c3 * NBINS;

    for (; i + stride < n4_per_img; i += 2 * stride) {
        iv4 v0 = p[i];
        iv4 v1 = p[i + stride];
        pk[i]          = (unsigned)(v0.x & 255) | ((unsigned)(v0.y & 255) << 8) |
                         ((unsigned)(v0.z & 255) << 16) | ((unsigned)(v0.w & 255) << 24);
        pk[i + stride] = (unsigned)(v1.x & 255) | ((unsigned)(v1.y & 255) << 8) |
                         ((unsigned)(v1.z & 255) << 16) | ((unsigned)(v1.w & 255) << 24);
        atomicAdd(&subh[wave][b0 + (v0.x & 255)], 1);
        atomicAdd(&subh[wave][b1 + (v0.y & 255)], 1);
        atomicAdd(&subh[wave][b2 + (v0.z & 255)], 1);
        atomicAdd(&subh[wave][b3 + (v0.w & 255)], 1);
        atomicAdd(&subh[wave][b0 + (v1.x & 255)], 1);
        atomicAdd(&subh[wave][b1 + (v1.y & 255)], 1);
        atomicAdd(&subh[wave][b2 + (v1.z & 255)], 1);
        atomicAdd(&subh[wave][b3 + (v1.w & 255)], 1);
    }
    if (i < n4_per_img) {
        iv4 v = p[i];
        pk[i] = (unsigned)(v.x & 255) | ((unsigned)(v.y & 255) << 8) |
                ((unsigned)(v.z & 255) << 16) | ((unsigned)(v.w & 255) << 24);
        atomicAdd(&subh[wave][b0 + (v.x & 255)], 1);
        atomicAdd(&subh[wave][b1 + (v.y & 255)], 1);
        atomicAdd(&subh[wave][b2 + (v.z & 255)], 1);
        atomicAdd(&subh[wave][b3 + (v.w & 255)], 1);
    }
    __syncthreads();

    int* gp = part + (size_t)blockIdx.x * HPI;  // own slot: plain store, no atomics
    for (int e = tid; e < HPI; e += 256)
        gp[e] = subh[0][e] + subh[1][e] + subh[2][e] + subh[3][e];
}

// ---------------- Kernel 2: reduce partials + LUT (wave-shfl scan, 3 barriers) ----
__global__ __launch_bounds__(256)
void lut_kernel(const int* __restrict__ part, int* __restrict__ lut) {
    __shared__ int waveTot[4];
    __shared__ int waveHi[4];
    __shared__ int hlS;

    const int t    = threadIdx.x;
    const int wave = t >> 6;
    const int lane = t & 63;
    const int img  = blockIdx.x / 3;
    const int ch   = blockIdx.x % 3;

    const int* p = part + (size_t)img * BPI * HPI + ch * NBINS + t;
    int h = 0;
    #pragma unroll 4
    for (int b = 0; b < BPI; ++b) h += p[(size_t)b * HPI];

    // inclusive scan within wave (no barriers)
    int cum = h;
    #pragma unroll
    for (int d = 1; d < 64; d <<= 1) {
        int v = __shfl_up(cum, d, 64);
        if (lane >= d) cum += v;
    }

    unsigned long long nzmask = __ballot(h > 0);
    if (lane == 63) waveTot[wave] = cum;
    if (lane == 0)
        waveHi[wave] = nzmask ? (wave * 64 + 63 - __clzll(nzmask)) : -1;
    __syncthreads();  // barrier 1

    int add = 0, sum = 0;
    #pragma unroll
    for (int w = 0; w < 4; ++w) {
        int tt = waveTot[w];
        if (w < wave) add += tt;
        sum += tt;
    }
    cum += add;

    int last = max(max(waveHi[0], waveHi[1]), max(waveHi[2], waveHi[3]));
    if (t == last) hlS = h;  // broadcast histo[last]
    __syncthreads();  // barrier 2

    const int step = (sum - hlS) / 255;
    int v;
    if (step == 0) {
        v = t;  // reference: where(step==0, img, ...)
    } else {
        const int cp = cum - h;  // exclusive prefix (== concat([0], cumsum[:-1]))
        v = (cp + (step >> 1)) / step;
        if (v > 255) v = 255;
    }
    lut[blockIdx.x * NBINS + t] = v;
}

// ---------------- Kernel 3: apply LUT (R8 exact form) ----------------
// 4B packed load per lane (dense 256B/wave-instr), one iv4 store per lane
// (dense 1024B/wave-instr). R12 lesson: widening loads to uint2 makes the
// per-instruction store pattern 50%-masked at 32B stride -> nt partial-line
// writes to HBM -> ~2x write cost. Keep load/store both instruction-dense.
__global__ __launch_bounds__(256)
void apply_kernel(const unsigned* __restrict__ packed, iv4* __restrict__ out,
                  const int* __restrict__ lut, int n4_per_img) {
    __shared__ int l[HPI];
    const int tid = threadIdx.x;
    const int img = blockIdx.x / BPI;
    const int blk = blockIdx.x % BPI;

    const int* gl = lut + (size_t)img * HPI;
    for (int i = tid; i < HPI; i += 256) l[i] = gl[i];
    __syncthreads();

    const size_t ibase = (size_t)img * n4_per_img;
    const unsigned* pk = packed + ibase;
    iv4* q = out + ibase;
    const int stride = BPI * 256;  // divisible by 3

    int i = blk * 256 + tid;
    int c0 = i % 3;
    int c1 = c0 + 1; if (c1 == 3) c1 = 0;
    int c2 = c1 + 1; if (c2 == 3) c2 = 0;
    int c3 = c2 + 1; if (c3 == 3) c3 = 0;
    const int b0 = c0 * NBINS, b1 = c1 * NBINS, b2 = c2 * NBINS, b3 = c3 * NBINS;

    for (; i + stride < n4_per_img; i += 2 * stride) {
        unsigned w0 = pk[i];
        unsigned w1 = pk[i + stride];
        iv4 o0, o1;
        o0.x = l[b0 + (w0 & 255)];
        o0.y = l[b1 + ((w0 >> 8) & 255)];
        o0.z = l[b2 + ((w0 >> 16) & 255)];
        o0.w = l[b3 + (w0 >> 24)];
        o1.x = l[b0 + (w1 & 255)];
        o1.y = l[b1 + ((w1 >> 8) & 255)];
        o1.z = l[b2 + ((w1 >> 16) & 255)];
        o1.w = l[b3 + (w1 >> 24)];
        __builtin_nontemporal_store(o0, &q[i]);           // output never re-read:
        __builtin_nontemporal_store(o1, &q[i + stride]);  // don't pollute LLC
    }
    if (i < n4_per_img) {
        unsigned w = pk[i];
        iv4 o;
        o.x = l[b0 + (w & 255)];
        o.y = l[b1 + ((w >> 8) & 255)];
        o.z = l[b2 + ((w >> 16) & 255)];
        o.w = l[b3 + (w >> 24)];
        __builtin_nontemporal_store(o, &q[i]);
    }
}

extern "C" void kernel_launch(void* const* d_in, const int* in_sizes, int n_in,
                              void* d_out, int out_size, void* d_ws, size_t ws_size,
                              hipStream_t stream) {
    const int* in = (const int*)d_in[0];
    int* out = (int*)d_out;

    const int npix = 512 * 512;
    const int ints_per_img = 3 * npix;
    const int n4_per_img = ints_per_img / 4;        // 196608 (= 32 * 6144)
    const int n_img = in_sizes[0] / ints_per_img;   // 64

    int* part = (int*)d_ws;                             // 1536*768 ints = 4.7 MB
    int* lut  = part + (size_t)n_img * BPI * HPI;       // 192 KB
    unsigned* packed = (unsigned*)(lut + (size_t)n_img * HPI);  // 50 MB

    hist_part_kernel<<<n_img * BPI, 256, 0, stream>>>((const iv4*)in, part, packed, n4_per_img);
    lut_kernel<<<n_img * 3, 256, 0, stream>>>(part, lut);
    apply_kernel<<<n_img * BPI, 256, 0, stream>>>(packed, (iv4*)out, lut, n4_per_img);
}